// Round 3
// baseline (332.915 us; speedup 1.0000x reference)
//
#include <hip/hip_runtime.h>
#include <math.h>

#define N_PTS 4096
#define KNN   16
#define DFEAT 64
#define DOUT  128
#define CTOT  192   // DOUT + DFEAT

// d2 exactly as reference: (sq_i + sq_j) - 2*dot, clamped at 0.
__device__ __forceinline__ float d2_of(float4 ci, float4 cj) {
    float dot = ci.x * cj.x + ci.y * cj.y + ci.z * cj.z;
    float d2  = (ci.w + cj.w) - 2.0f * dot;
    return fmaxf(d2, 0.0f);
}

// ---------------- Kernel 1: exact KNN (top-16 ascending, stable ties) ----
// 1024 threads = 16 waves; one wave per query point. Whole batch's coords
// staged in LDS as float4{x,y,z,sq} (64 KB -> 2 blocks/CU, 32 waves/CU).
// Each lane owns candidates j = t*64 + lane (t = 0..63) and tracks its
// local top-2 plus a 64-bit `taken` mask of already-extracted slots, so
// the (rare) rescan is pure integer bookkeeping — no dependence on FP
// bit-identity between compiles of the distance expression.
__global__ void knn_kernel(const float* __restrict__ coords,
                           int* __restrict__ idx_ws,
                           float* __restrict__ dist_ws)
{
    __shared__ float4 cs[N_PTS];
    const int tid = threadIdx.x;
    const int q0  = blockIdx.x * 16;     // first query handled by this block
    const int b   = q0 >> 12;            // q0 / N_PTS

    const float* cb = coords + (size_t)b * N_PTS * 3;
    for (int j = tid; j < N_PTS; j += 1024) {
        float x = cb[j * 3 + 0], y = cb[j * 3 + 1], z = cb[j * 3 + 2];
        float sq = x * x + y * y + z * z;
        cs[j] = make_float4(x, y, z, sq);
    }
    __syncthreads();

    const int wave = tid >> 6;
    const int lane = tid & 63;
    const int q = q0 + wave;             // global query id
    const int n = q & (N_PTS - 1);       // index within batch

    const float4 ci = cs[n];

    const float SENT  = 3.0e38f;
    const int   JSENT = 0x7fffffff;
    float m1 = SENT, m2 = SENT;
    int   j1 = JSENT, j2 = JSENT;

    // Scan: consecutive j across lanes -> full-bandwidth ds_read_b128.
    // Within a lane j is strictly increasing, so strict < keeps the
    // earliest index at equal d (lax.top_k stable tie order).
    for (int t = 0; t < 64; ++t) {
        int   j = (t << 6) + lane;
        float d = d2_of(ci, cs[j]);
        bool lt1 = (d < m1);
        bool lt2 = (d < m2);
        float nm2 = lt1 ? m1 : (lt2 ? d : m2);
        int   nj2 = lt1 ? j1 : (lt2 ? j : j2);
        m1 = lt1 ? d : m1;  j1 = lt1 ? j : j1;
        m2 = nm2;           j2 = nj2;
    }

    unsigned long long taken = 0ull;     // this lane's extracted slots
    float outd = 0.0f; int outj = 0;

    for (int k = 0; k < KNN; ++k) {
        // wave-wide lexicographic argmin over (m1, j1)
        float rm = m1; int rj = j1;
        #pragma unroll
        for (int s = 1; s < 64; s <<= 1) {
            float om = __shfl_xor(rm, s);
            int   oj = __shfl_xor(rj, s);
            if (om < rm || (om == rm && oj < rj)) { rm = om; rj = oj; }
        }
        // (rm, rj) is wave-uniform: the k-th nearest neighbor
        if (lane == k) { outd = rm; outj = rj; }

        // owner removes its winner (j is unique across lanes: j%64==lane)
        if (j1 == rj) {
            taken |= 1ull << (j1 >> 6);
            m1 = m2; j1 = j2;
            m2 = SENT; j2 = JSENT;
        }

        // lane exhausted its known top-2: rebuild true top-2 of its
        // remaining (non-taken) candidates. Expected ~1-2x per query.
        if (j1 == JSENT && k < KNN - 1) {
            m1 = SENT; m2 = SENT; j1 = JSENT; j2 = JSENT;
            for (int t = 0; t < 64; ++t) {
                if ((taken >> t) & 1ull) continue;
                int   j = (t << 6) + lane;
                float d = d2_of(ci, cs[j]);
                bool lt1 = (d < m1);
                bool lt2 = (d < m2);
                float nm2 = lt1 ? m1 : (lt2 ? d : m2);
                int   nj2 = lt1 ? j1 : (lt2 ? j : j2);
                m1 = lt1 ? d : m1;  j1 = lt1 ? j : j1;
                m2 = nm2;           j2 = nj2;
            }
        }
    }

    if (lane < KNN) {
        idx_ws[q * KNN + lane]  = outj;
        dist_ws[q * KNN + lane] = sqrtf(fmaxf(outd, 1e-12f));
    }
}

// ---------------- Kernel 2: encode + 1x1-conv MLP + feature concat --------
// One thread per (b, n, k); consecutive threads = consecutive (n*16+k) so
// every per-channel store is a fully coalesced 1 KB/wave write.
__global__ __launch_bounds__(256) void out_kernel(
    const float* __restrict__ coords, const float* __restrict__ features,
    const float* __restrict__ W, const float* __restrict__ bias,
    const int* __restrict__ idx_ws, const float* __restrict__ dist_ws,
    float* __restrict__ out)
{
    __shared__ float Ws[DOUT * 12];   // rows padded 10 -> 12 for b128 reads
    __shared__ float bs[DOUT];
    const int tid = threadIdx.x;
    for (int i = tid; i < DOUT * 12; i += 256) {
        int o = i / 12, t = i - o * 12;
        Ws[i] = (t < 10) ? W[o * 10 + t] : 0.0f;
    }
    if (tid < DOUT) bs[tid] = bias[tid];
    __syncthreads();

    const int g = blockIdx.x * 256 + tid;     // flat (b, n, k)
    const int k = g & (KNN - 1);
    const int n = (g >> 4) & (N_PTS - 1);
    const int b = g >> 16;

    const float* cb = coords + (size_t)b * N_PTS * 3;
    const int   nb   = idx_ws[g];
    const float dist = dist_ws[g];
    const float pix = cb[n * 3 + 0],  piy = cb[n * 3 + 1],  piz = cb[n * 3 + 2];
    const float pjx = cb[nb * 3 + 0], pjy = cb[nb * 3 + 1], pjz = cb[nb * 3 + 2];

    const float e0 = pix, e1 = piy, e2 = piz;
    const float e3 = pjx, e4 = pjy, e5 = pjz;
    const float e6 = pix - pjx, e7 = piy - pjy, e8 = piz - pjz, e9 = dist;

    float* outb = out + (size_t)b * CTOT * N_PTS * KNN + (size_t)n * KNN + k;
    #pragma unroll 4
    for (int o = 0; o < DOUT; ++o) {
        const float4 w0 = *reinterpret_cast<const float4*>(&Ws[o * 12 + 0]);
        const float4 w1 = *reinterpret_cast<const float4*>(&Ws[o * 12 + 4]);
        const float2 w2 = *reinterpret_cast<const float2*>(&Ws[o * 12 + 8]);
        float acc = bs[o]
            + e0 * w0.x + e1 * w0.y + e2 * w0.z + e3 * w0.w
            + e4 * w1.x + e5 * w1.y + e6 * w1.z + e7 * w1.w
            + e8 * w2.x + e9 * w2.y;
        outb[(size_t)o * (N_PTS * KNN)] = acc;
    }

    const float* fb = features + (size_t)b * DFEAT * N_PTS + n;
    float* outf = outb + (size_t)DOUT * (N_PTS * KNN);
    #pragma unroll 4
    for (int f = 0; f < DFEAT; ++f) {
        outf[(size_t)f * (N_PTS * KNN)] = fb[(size_t)f * N_PTS];
    }
}

extern "C" void kernel_launch(void* const* d_in, const int* in_sizes, int n_in,
                              void* d_out, int out_size, void* d_ws, size_t ws_size,
                              hipStream_t stream) {
    (void)n_in; (void)out_size; (void)ws_size;
    const float* coords   = (const float*)d_in[0];
    const float* features = (const float*)d_in[1];
    const float* W        = (const float*)d_in[2];
    const float* bias     = (const float*)d_in[3];
    float* out = (float*)d_out;

    const int B  = in_sizes[0] / (N_PTS * 3);   // 4
    const int nq = B * N_PTS;                   // 16384 queries

    int*   idx_ws  = (int*)d_ws;
    float* dist_ws = (float*)((char*)d_ws + (size_t)nq * KNN * sizeof(int));

    knn_kernel<<<nq / 16, 1024, 0, stream>>>(coords, idx_ws, dist_ws);
    out_kernel<<<(nq * KNN) / 256, 256, 0, stream>>>(
        coords, features, W, bias, idx_ws, dist_ws, out);
}

// Round 6
// 305.779 us; speedup vs baseline: 1.0887x; 1.0887x over previous
//
#include <hip/hip_runtime.h>
#include <math.h>

#define N_PTS 4096
#define KNN   16
#define DFEAT 64
#define DOUT  128
#define CTOT  192   // DOUT + DFEAT

#define QPB   32    // queries per block = 16 waves x 2 halves
#define LPQ   32    // lanes per query (half-wave)

// Packed ranking key: hi32 = float bits of d2 (>= 0 so unsigned order ==
// float order), lo32 = j. Unsigned 64-bit compare == lexicographic (d2, j),
// exactly lax.top_k's stable tie-break. d2 formula identical to reference:
// (sq_i + sq_j) - 2*dot, clamped at 0.
__device__ __forceinline__ unsigned long long key_of(float4 ci, float4 cj, int j) {
    float dot = ci.x * cj.x + ci.y * cj.y + ci.z * cj.z;
    float d2  = fmaxf((ci.w + cj.w) - 2.0f * dot, 0.0f);
    return ((unsigned long long)__float_as_uint(d2) << 32) | (unsigned)j;
}

// Branchless sorted insert into ascending 4-list k1<=k2<=k3<=k4.
#define INSERT4(kk)                                   \
    do {                                              \
        bool c1 = (kk) < k1, c2 = (kk) < k2;          \
        bool c3 = (kk) < k3, c4 = (kk) < k4;          \
        k4 = c3 ? k3 : (c4 ? (kk) : k4);              \
        k3 = c2 ? k2 : (c3 ? (kk) : k3);              \
        k2 = c1 ? k1 : (c2 ? (kk) : k2);              \
        k1 = c1 ? (kk) : k1;                          \
    } while (0)

// ---------------- Kernel 1: exact KNN (top-16 ascending, stable ties) ----
// 1024 threads = 16 waves; each wave handles TWO queries (32 lanes each).
// Whole batch's coords staged in LDS as float4{x,y,z,sq} (64 KB). Each
// half-lane owns candidates j = t*32 + hl (t = 0..127), keeps a sorted
// top-4 of packed u64 keys; 16 extraction rounds of a 5-stage shfl_xor
// min-reduce (both halves concurrently). A lane needs a rescan only if it
// owns >= 5 of the true top-16 (P ~ 0.4%/query) — integer taken-bitmask
// rescan path retained for exactness, branch-skipped when idle.
__global__ __launch_bounds__(1024) void knn_kernel(
    const float* __restrict__ coords,
    int* __restrict__ idx_ws,
    float* __restrict__ dist_ws)
{
    __shared__ float4 cs[N_PTS];
    const int tid = threadIdx.x;
    const int q0  = blockIdx.x * QPB;
    const int b   = q0 >> 12;            // all QPB queries share a batch

    const float* cb = coords + (size_t)b * N_PTS * 3;
    for (int j = tid; j < N_PTS; j += 1024) {
        float x = cb[j * 3 + 0], y = cb[j * 3 + 1], z = cb[j * 3 + 2];
        cs[j] = make_float4(x, y, z, x * x + y * y + z * z);
    }
    __syncthreads();

    const int wave = tid >> 6;
    const int lane = tid & 63;
    const int half = lane >> 5;          // which of the wave's 2 queries
    const int hl   = lane & 31;          // lane index within the query group
    const int q    = q0 + wave * 2 + half;
    const int n    = q & (N_PTS - 1);

    const float4 ci = cs[n];

    const unsigned long long KSENT = 0xFFFFFFFFFFFFFFFFull;
    unsigned long long k1 = KSENT, k2 = KSENT, k3 = KSENT, k4 = KSENT;

    // Scan: consecutive j across the 32 half-lanes; the two halves read
    // identical LDS addresses (broadcast). Sorted top-4 per lane.
    for (int t = 0; t < 128; ++t) {
        int j = (t << 5) + hl;
        unsigned long long kk = key_of(ci, cs[j], j);
        INSERT4(kk);
    }

    unsigned long long tak0 = 0ull, tak1 = 0ull;  // extracted slots (t<64 / t>=64)
    unsigned long long outKey = 0ull;

    for (int k = 0; k < KNN; ++k) {
        // 5-stage half-wave min-reduce on the u64 key (xor s<32 stays in half)
        unsigned long long rk = k1;
        #pragma unroll
        for (int s = 1; s < LPQ; s <<= 1) {
            unsigned long long o = __shfl_xor(rk, s);
            if (o < rk) rk = o;
        }
        // rk is uniform within the half: the k-th nearest neighbor
        if (hl == k) outKey = rk;

        // owner removes its winner (keys are globally unique: lo word = j)
        if (k1 == rk) {
            int t = (int)(rk & 0xFFFFFFFFull) >> 5;
            if (t < 64) tak0 |= 1ull << t;
            else        tak1 |= 1ull << (t - 64);
            k1 = k2; k2 = k3; k3 = k4; k4 = KSENT;
        }

        // lane exhausted its top-4 (won 4 times): rebuild from LDS,
        // skipping taken slots. ~0.4% of queries; exec-masked + branch-skipped.
        if (k1 == KSENT && k < KNN - 1) {
            k2 = KSENT; k3 = KSENT; k4 = KSENT;
            for (int t = 0; t < 64; ++t) {
                if ((tak0 >> t) & 1ull) continue;
                int j = (t << 5) + hl;
                unsigned long long kk = key_of(ci, cs[j], j);
                INSERT4(kk);
            }
            for (int t = 64; t < 128; ++t) {
                if ((tak1 >> (t - 64)) & 1ull) continue;
                int j = (t << 5) + hl;
                unsigned long long kk = key_of(ci, cs[j], j);
                INSERT4(kk);
            }
        }
    }

    if (hl < KNN) {
        float d2 = __uint_as_float((unsigned)(outKey >> 32));
        idx_ws[q * KNN + hl]  = (int)(outKey & 0xFFFFFFFFull);
        dist_ws[q * KNN + hl] = sqrtf(fmaxf(d2, 1e-12f));
    }
}

// ---------------- Kernel 2: encode + 1x1-conv MLP + feature concat --------
// (unchanged from round 3 — isolating the knn delta; its counters will
// surface in top-5 once knn drops below it)
__global__ __launch_bounds__(256) void out_kernel(
    const float* __restrict__ coords, const float* __restrict__ features,
    const float* __restrict__ W, const float* __restrict__ bias,
    const int* __restrict__ idx_ws, const float* __restrict__ dist_ws,
    float* __restrict__ out)
{
    __shared__ float Ws[DOUT * 12];   // rows padded 10 -> 12 for b128 reads
    __shared__ float bs[DOUT];
    const int tid = threadIdx.x;
    for (int i = tid; i < DOUT * 12; i += 256) {
        int o = i / 12, t = i - o * 12;
        Ws[i] = (t < 10) ? W[o * 10 + t] : 0.0f;
    }
    if (tid < DOUT) bs[tid] = bias[tid];
    __syncthreads();

    const int g = blockIdx.x * 256 + tid;     // flat (b, n, k)
    const int k = g & (KNN - 1);
    const int n = (g >> 4) & (N_PTS - 1);
    const int b = g >> 16;

    const float* cb = coords + (size_t)b * N_PTS * 3;
    const int   nb   = idx_ws[g];
    const float dist = dist_ws[g];
    const float pix = cb[n * 3 + 0],  piy = cb[n * 3 + 1],  piz = cb[n * 3 + 2];
    const float pjx = cb[nb * 3 + 0], pjy = cb[nb * 3 + 1], pjz = cb[nb * 3 + 2];

    const float e0 = pix, e1 = piy, e2 = piz;
    const float e3 = pjx, e4 = pjy, e5 = pjz;
    const float e6 = pix - pjx, e7 = piy - pjy, e8 = piz - pjz, e9 = dist;

    float* outb = out + (size_t)b * CTOT * N_PTS * KNN + (size_t)n * KNN + k;
    #pragma unroll 4
    for (int o = 0; o < DOUT; ++o) {
        const float4 w0 = *reinterpret_cast<const float4*>(&Ws[o * 12 + 0]);
        const float4 w1 = *reinterpret_cast<const float4*>(&Ws[o * 12 + 4]);
        const float2 w2 = *reinterpret_cast<const float2*>(&Ws[o * 12 + 8]);
        float acc = bs[o]
            + e0 * w0.x + e1 * w0.y + e2 * w0.z + e3 * w0.w
            + e4 * w1.x + e5 * w1.y + e6 * w1.z + e7 * w1.w
            + e8 * w2.x + e9 * w2.y;
        outb[(size_t)o * (N_PTS * KNN)] = acc;
    }

    const float* fb = features + (size_t)b * DFEAT * N_PTS + n;
    float* outf = outb + (size_t)DOUT * (N_PTS * KNN);
    #pragma unroll 4
    for (int f = 0; f < DFEAT; ++f) {
        outf[(size_t)f * (N_PTS * KNN)] = fb[(size_t)f * N_PTS];
    }
}

extern "C" void kernel_launch(void* const* d_in, const int* in_sizes, int n_in,
                              void* d_out, int out_size, void* d_ws, size_t ws_size,
                              hipStream_t stream) {
    (void)n_in; (void)out_size; (void)ws_size;
    const float* coords   = (const float*)d_in[0];
    const float* features = (const float*)d_in[1];
    const float* W        = (const float*)d_in[2];
    const float* bias     = (const float*)d_in[3];
    float* out = (float*)d_out;

    const int B  = in_sizes[0] / (N_PTS * 3);   // 4
    const int nq = B * N_PTS;                   // 16384 queries

    int*   idx_ws  = (int*)d_ws;
    float* dist_ws = (float*)((char*)d_ws + (size_t)nq * KNN * sizeof(int));

    knn_kernel<<<nq / QPB, 1024, 0, stream>>>(coords, idx_ws, dist_ws);
    out_kernel<<<(nq * KNN) / 256, 256, 0, stream>>>(
        coords, features, W, bias, idx_ws, dist_ws, out);
}